// Round 3
// baseline (199.733 us; speedup 1.0000x reference)
//
#include <hip/hip_runtime.h>

// YOLO-style multi-level detection loss.
// Input dict order (setup_inputs interleaves!):
//   d_in[0]=cls0 d_in[1]=box0 d_in[2]=obj0
//   d_in[3]=cls1 d_in[4]=box1 d_in[5]=obj1
//   d_in[6]=cls2 d_in[7]=box2 d_in[8]=obj2
//   d_in[9]=boxes [B,N,4]  d_in[10]=labels [B,N]
// Output: 4 floats: total, loss_cls, loss_box, loss_obj
//
// Strategy: never materialize target tensors. bce(x,t) = bce(x,0) - x*t for
// t in {0,1}. Scatter records per cell: winner box index (atomicMax -> last
// box wins, matching JAX CPU sequential scatter-set) and 20-bit label mask
// (atomicOr, exact under collisions). Reduce touches cls/box preds only at
// positive cells. 4 dispatches total.

#define NCLS  20
#define BATCH 128
#define NBOX  64
#define TPB   256
#define NB_RED 256
// cells per level (BATCH * H * W)
#define C0 819200
#define C1 204800
#define C2 51200
#define CT (C0 + C1 + C2)   // 1,075,200
// reduce-block partition: blocks [0,192) -> lvl0, [192,240) -> lvl1, [240,256) -> lvl2
#define B0 192
#define B1 48
#define B2 16

struct AllPtrs {
    const float *cls0, *box0, *obj0;
    const float *cls1, *box1, *obj1;
    const float *cls2, *box2, *obj2;
};

__device__ __forceinline__ float bce0(float x) {
    // bce_with_logits(x, 0) = max(x,0) + log1p(exp(-|x|))
    return fmaxf(x, 0.0f) + log1pf(expf(-fabsf(x)));
}

__device__ __forceinline__ float wave_sum(float v) {
    #pragma unroll
    for (int o = 32; o > 0; o >>= 1) v += __shfl_down(v, o);
    return v;
}

__global__ void init_grids(int4* __restrict__ winner, uint4* __restrict__ clsmask) {
    int i = blockIdx.x * blockDim.x + threadIdx.x;   // CT/4 = 268800 threads
    if (i < CT / 4) {
        winner[i]  = make_int4(-1, -1, -1, -1);
        clsmask[i] = make_uint4(0u, 0u, 0u, 0u);
    }
}

__global__ void scatter_boxes(const float4* __restrict__ boxes, const int* __restrict__ labels,
                              int* __restrict__ winner, unsigned* __restrict__ clsmask) {
    int t = blockIdx.x * blockDim.x + threadIdx.x;
    if (t >= BATCH * NBOX) return;
    int b = t >> 6;          // NBOX == 64
    int n = t & 63;
    float4 bx = boxes[t];
    float cx = (bx.x + bx.z) * 0.5f;
    float cy = (bx.y + bx.w) * 0.5f;
    unsigned lb = 1u << labels[t];
    const int   offs[3] = {0, C0, C0 + C1};
    const int   Hs[3]   = {80, 40, 20};
    const float is[3]   = {0.125f, 0.0625f, 0.03125f};
    #pragma unroll
    for (int l = 0; l < 3; ++l) {
        int H = Hs[l], W = Hs[l];
        int gx = (int)floorf(cx * is[l]);
        int gy = (int)floorf(cy * is[l]);
        if (gx >= 0 && gy >= 0 && gx < W && gy < H) {
            int cell = offs[l] + (b * H + gy) * W + gx;
            atomicMax(winner + cell, n);
            atomicOr(clsmask + cell, lb);
        }
    }
}

__global__ void __launch_bounds__(TPB)
reduce_all(AllPtrs p, const float4* __restrict__ boxes,
           const int* __restrict__ winner, const unsigned* __restrict__ clsmask,
           float* __restrict__ partials) {
    int blk = blockIdx.x;
    const float *obj, *cls, *boxp;
    int HW, off, blk0, nblk;
    float inv_stride;
    if (blk < B0) {
        obj = p.obj0; cls = p.cls0; boxp = p.box0;
        HW = 6400; off = 0; blk0 = 0; nblk = B0; inv_stride = 0.125f;
    } else if (blk < B0 + B1) {
        obj = p.obj1; cls = p.cls1; boxp = p.box1;
        HW = 1600; off = C0; blk0 = B0; nblk = B1; inv_stride = 0.0625f;
    } else {
        obj = p.obj2; cls = p.cls2; boxp = p.box2;
        HW = 400; off = C0 + C1; blk0 = B0 + B1; nblk = B2; inv_stride = 0.03125f;
    }
    const int total = BATCH * HW;
    float a_obj = 0.f, a_np = 0.f, a_cls = 0.f, a_box = 0.f;
    for (int i = (blk - blk0) * TPB + threadIdx.x; i < total; i += nblk * TPB) {
        float x = obj[i];
        float v = bce0(x);               // bce(obj, 0)
        int wn = winner[off + i];
        if (wn >= 0) {                   // positive cell
            int b = i / HW, rem = i - b * HW;
            v -= x;                      // -> bce(obj, 1)
            a_np += 1.f;
            unsigned m = clsmask[off + i];
            const float* cb = cls + (b * NCLS) * HW + rem;
            #pragma unroll
            for (int c = 0; c < NCLS; ++c) {
                float cv = cb[c * HW];
                a_cls += bce0(cv);
                if ((m >> c) & 1u) a_cls -= cv;   // bce(cv,1) = bce(cv,0) - cv
            }
            // rebuild box target from the winning (last) box
            float4 bx = boxes[(b << 6) + wn];
            float cx = (bx.x + bx.z) * 0.5f, cy = (bx.y + bx.w) * 0.5f;
            float w  = bx.z - bx.x,          h  = bx.w - bx.y;
            float sx = cx * inv_stride,      sy = cy * inv_stride;
            float tv0 = sx - floorf(sx);
            float tv1 = sy - floorf(sy);
            float tv2 = logf(w * inv_stride + 1e-6f);
            float tv3 = logf(h * inv_stride + 1e-6f);
            const float* pb = boxp + (b * 4) * HW + rem;
            float d0 = fabsf(pb[0]          - tv0);
            float d1 = fabsf(pb[HW]         - tv1);
            float d2 = fabsf(pb[2 * HW]     - tv2);
            float d3 = fabsf(pb[3 * HW]     - tv3);
            a_box += (d0 < 1.f) ? 0.5f * d0 * d0 : d0 - 0.5f;
            a_box += (d1 < 1.f) ? 0.5f * d1 * d1 : d1 - 0.5f;
            a_box += (d2 < 1.f) ? 0.5f * d2 * d2 : d2 - 0.5f;
            a_box += (d3 < 1.f) ? 0.5f * d3 * d3 : d3 - 0.5f;
        }
        a_obj += v;
    }
    a_obj = wave_sum(a_obj); a_np = wave_sum(a_np);
    a_cls = wave_sum(a_cls); a_box = wave_sum(a_box);
    __shared__ float s[TPB / 64][4];
    int wid = threadIdx.x >> 6, lane = threadIdx.x & 63;
    if (lane == 0) { s[wid][0] = a_obj; s[wid][1] = a_np; s[wid][2] = a_cls; s[wid][3] = a_box; }
    __syncthreads();
    if (threadIdx.x == 0) {
        float o = 0, np = 0, c = 0, bo = 0;
        #pragma unroll
        for (int w2 = 0; w2 < TPB / 64; ++w2) {
            o += s[w2][0]; np += s[w2][1]; c += s[w2][2]; bo += s[w2][3];
        }
        float4* pp = (float4*)(partials + blk * 4);
        *pp = make_float4(o, np, c, bo);
    }
}

__global__ void final_combine(const float* __restrict__ partials, float* __restrict__ out) {
    int t = threadIdx.x;                 // 256 threads, one per reduce block
    float4 v = ((const float4*)partials)[t];
    int seg = (t < B0) ? 0 : (t < B0 + B1 ? 1 : 2);
    const float inv_cnt[3] = {1.f / (float)C0, 1.f / (float)C1, 1.f / (float)C2};
    __shared__ float s[4][4];
    __shared__ float acc[3];             // cls, box, obj
    if (t < 3) acc[t] = 0.f;
    __syncthreads();
    for (int lvl = 0; lvl < 3; ++lvl) {
        float o  = (seg == lvl) ? v.x : 0.f;
        float np = (seg == lvl) ? v.y : 0.f;
        float c  = (seg == lvl) ? v.z : 0.f;
        float bo = (seg == lvl) ? v.w : 0.f;
        o = wave_sum(o); np = wave_sum(np); c = wave_sum(c); bo = wave_sum(bo);
        int wid = t >> 6, lane = t & 63;
        if (lane == 0) { s[wid][0] = o; s[wid][1] = np; s[wid][2] = c; s[wid][3] = bo; }
        __syncthreads();
        if (t == 0) {
            float O = 0, NP = 0, C = 0, BO = 0;
            #pragma unroll
            for (int w = 0; w < 4; ++w) { O += s[w][0]; NP += s[w][1]; C += s[w][2]; BO += s[w][3]; }
            NP = fmaxf(NP, 1.f);
            acc[0] += C / NP;
            acc[1] += BO / NP;
            acc[2] += O * inv_cnt[lvl];
        }
        __syncthreads();
    }
    if (t == 0) {
        float lc = acc[0], lb = acc[1], lo = acc[2];
        out[0] = lc + lb + lo;
        out[1] = lc;
        out[2] = lb;
        out[3] = lo;
    }
}

extern "C" void kernel_launch(void* const* d_in, const int* in_sizes, int n_in,
                              void* d_out, int out_size, void* d_ws, size_t ws_size,
                              hipStream_t stream) {
    AllPtrs p;
    p.cls0 = (const float*)d_in[0]; p.box0 = (const float*)d_in[1]; p.obj0 = (const float*)d_in[2];
    p.cls1 = (const float*)d_in[3]; p.box1 = (const float*)d_in[4]; p.obj1 = (const float*)d_in[5];
    p.cls2 = (const float*)d_in[6]; p.box2 = (const float*)d_in[7]; p.obj2 = (const float*)d_in[8];
    const float4* boxes  = (const float4*)d_in[9];
    const int*    labels = (const int*)d_in[10];
    float* out = (float*)d_out;

    // workspace: winner[CT] int, clsmask[CT] unsigned, partials[NB_RED*4] float
    char* ws = (char*)d_ws;
    int*      winner   = (int*)ws;                      // 4,300,800 B
    unsigned* clsmask  = (unsigned*)(ws + CT * 4);      // 4,300,800 B
    float*    partials = (float*)(ws + (size_t)CT * 8); // 4,096 B

    init_grids<<<(CT / 4 + TPB - 1) / TPB, TPB, 0, stream>>>((int4*)winner, (uint4*)clsmask);
    scatter_boxes<<<(BATCH * NBOX + TPB - 1) / TPB, TPB, 0, stream>>>(boxes, labels, winner, clsmask);
    reduce_all<<<NB_RED, TPB, 0, stream>>>(p, boxes, winner, clsmask, partials);
    final_combine<<<1, TPB, 0, stream>>>(partials, out);
}

// Round 6
// 90.507 us; speedup vs baseline: 2.2068x; 2.2068x over previous
//
#include <hip/hip_runtime.h>

// YOLO-style multi-level detection loss.
// Input dict order (setup_inputs interleaves!):
//   d_in[0]=cls0 d_in[1]=box0 d_in[2]=obj0
//   d_in[3]=cls1 d_in[4]=box1 d_in[5]=obj1
//   d_in[6]=cls2 d_in[7]=box2 d_in[8]=obj2
//   d_in[9]=boxes [B,N,4]  d_in[10]=labels [B,N]
// Output: 4 floats: total, loss_cls, loss_box, loss_obj
//
// bce(x,t) = bce(x,0) - x*t for t in {0,1} -> never materialize targets.
// Two per-cell arrays (a single packed word is WRONG: atomicMax clobbers
// accumulated label bits on collision cells):
//   winner[cell]  = max over boxes of (n+1)   (atomicMax; last box wins,
//                   matching JAX CPU sequential scatter-set; 0 = negative)
//   clsmask[cell] = OR of (1<<label)          (atomicOr; exact)
// Round-3 lesson: 256 blocks = 1 wave/SIMD = latency-bound (210us even fully
// cached). Now 1050 blocks, one float4 cell-quad per thread, no loops;
// clsmask fetched only at positive cells (~1%).

#define NCLS  20
#define BATCH 128
#define TPB   256
// cells per level (BATCH * H * W)
#define C0 819200
#define C1 204800
#define C2 51200
#define CT (C0 + C1 + C2)        // 1,075,200
// reduce blocks per level: cells/4/TPB (exact)
#define NBV0 800
#define NBV1 200
#define NBV2 50
#define NBLK (NBV0 + NBV1 + NBV2)  // 1050

struct AllPtrs {
    const float *cls0, *box0, *obj0;
    const float *cls1, *box1, *obj1;
    const float *cls2, *box2, *obj2;
};

__device__ __forceinline__ float bce0(float x) {
    // bce_with_logits(x, 0) = max(x,0) + log1p(exp(-|x|))
    return fmaxf(x, 0.0f) + log1pf(expf(-fabsf(x)));
}

__device__ __forceinline__ float wave_sum(float v) {
    #pragma unroll
    for (int o = 32; o > 0; o >>= 1) v += __shfl_down(v, o);
    return v;
}

__global__ void scatter_boxes(const float4* __restrict__ boxes, const int* __restrict__ labels,
                              unsigned* __restrict__ winner, unsigned* __restrict__ clsmask) {
    int t = blockIdx.x * blockDim.x + threadIdx.x;
    if (t >= BATCH * 64) return;
    int b = t >> 6;
    int n = t & 63;
    float4 bx = boxes[t];
    float cx = (bx.x + bx.z) * 0.5f;
    float cy = (bx.y + bx.w) * 0.5f;
    unsigned wv = (unsigned)(n + 1);
    unsigned lb = 1u << labels[t];
    const int   offs[3] = {0, C0, C0 + C1};
    const int   Hs[3]   = {80, 40, 20};
    const float is[3]   = {0.125f, 0.0625f, 0.03125f};
    #pragma unroll
    for (int l = 0; l < 3; ++l) {
        int H = Hs[l], W = Hs[l];
        int gx = (int)floorf(cx * is[l]);
        int gy = (int)floorf(cy * is[l]);
        if (gx >= 0 && gy >= 0 && gx < W && gy < H) {
            int cell = offs[l] + (b * H + gy) * W + gx;
            atomicMax(winner + cell, wv);
            atomicOr(clsmask + cell, lb);
        }
    }
}

struct Acc { float obj, np, cls, box; };

template<int HW>
__device__ __forceinline__ void proc4(int i, float4 ov, uint4 wq,
                                      const unsigned* __restrict__ clsmask,
                                      const float* __restrict__ cls,
                                      const float* __restrict__ boxp,
                                      const float4* __restrict__ boxes,
                                      float inv_stride, Acc& a) {
    const float    o[4] = {ov.x, ov.y, ov.z, ov.w};
    const unsigned g[4] = {wq.x, wq.y, wq.z, wq.w};
    #pragma unroll
    for (int j = 0; j < 4; ++j) {
        float x = o[j];
        float v = bce0(x);                 // bce(obj, 0)
        if (g[j]) {                        // positive cell
            int cell = i * 4 + j;
            int b = cell / HW, rem = cell - b * HW;
            int wn = (int)g[j] - 1;
            unsigned m = clsmask[cell];    // rare scalar load (~1% of cells)
            v -= x;                        // -> bce(obj, 1)
            a.np += 1.f;
            const float* cb = cls + (b * NCLS) * HW + rem;
            #pragma unroll
            for (int c = 0; c < NCLS; ++c) {
                float cv = cb[c * HW];
                a.cls += bce0(cv);
                if ((m >> c) & 1u) a.cls -= cv;   // bce(cv,1) = bce(cv,0) - cv
            }
            float4 bx = boxes[(b << 6) + wn];
            float cx = (bx.x + bx.z) * 0.5f, cy = (bx.y + bx.w) * 0.5f;
            float w  = bx.z - bx.x,          h  = bx.w - bx.y;
            float sx = cx * inv_stride,      sy = cy * inv_stride;
            float tv0 = sx - floorf(sx);
            float tv1 = sy - floorf(sy);
            float tv2 = logf(w * inv_stride + 1e-6f);
            float tv3 = logf(h * inv_stride + 1e-6f);
            const float* pb = boxp + (b * 4) * HW + rem;
            float d0 = fabsf(pb[0]      - tv0);
            float d1 = fabsf(pb[HW]     - tv1);
            float d2 = fabsf(pb[2 * HW] - tv2);
            float d3 = fabsf(pb[3 * HW] - tv3);
            a.box += (d0 < 1.f) ? 0.5f * d0 * d0 : d0 - 0.5f;
            a.box += (d1 < 1.f) ? 0.5f * d1 * d1 : d1 - 0.5f;
            a.box += (d2 < 1.f) ? 0.5f * d2 * d2 : d2 - 0.5f;
            a.box += (d3 < 1.f) ? 0.5f * d3 * d3 : d3 - 0.5f;
        }
        a.obj += v;
    }
}

__global__ void __launch_bounds__(TPB)
reduce_all(AllPtrs p, const float4* __restrict__ boxes,
           const uint4* __restrict__ winner4, const unsigned* __restrict__ clsmask,
           float4* __restrict__ partials) {
    int blk = blockIdx.x;
    Acc a = {0.f, 0.f, 0.f, 0.f};
    if (blk < NBV0) {
        int i = blk * TPB + threadIdx.x;
        proc4<6400>(i, ((const float4*)p.obj0)[i], winner4[i], clsmask,
                    p.cls0, p.box0, boxes, 0.125f, a);
    } else if (blk < NBV0 + NBV1) {
        int i = (blk - NBV0) * TPB + threadIdx.x;
        proc4<1600>(i, ((const float4*)p.obj1)[i], winner4[C0 / 4 + i], clsmask + C0,
                    p.cls1, p.box1, boxes, 0.0625f, a);
    } else {
        int i = (blk - NBV0 - NBV1) * TPB + threadIdx.x;
        proc4<400>(i, ((const float4*)p.obj2)[i], winner4[(C0 + C1) / 4 + i], clsmask + C0 + C1,
                    p.cls2, p.box2, boxes, 0.03125f, a);
    }
    float ro = wave_sum(a.obj), rn = wave_sum(a.np);
    float rc = wave_sum(a.cls), rb = wave_sum(a.box);
    __shared__ float s[TPB / 64][4];
    int wid = threadIdx.x >> 6, lane = threadIdx.x & 63;
    if (lane == 0) { s[wid][0] = ro; s[wid][1] = rn; s[wid][2] = rc; s[wid][3] = rb; }
    __syncthreads();
    if (threadIdx.x == 0) {
        float o = 0, np = 0, c = 0, bo = 0;
        #pragma unroll
        for (int w = 0; w < TPB / 64; ++w) {
            o += s[w][0]; np += s[w][1]; c += s[w][2]; bo += s[w][3];
        }
        partials[blk] = make_float4(o, np, c, bo);
    }
}

__global__ void final_combine(const float4* __restrict__ partials, float* __restrict__ out) {
    int t = threadIdx.x;
    float o0 = 0, n0 = 0, c0 = 0, b0 = 0;
    float o1 = 0, n1 = 0, c1 = 0, b1 = 0;
    float o2 = 0, n2 = 0, c2 = 0, b2 = 0;
    for (int e = t; e < NBV0; e += TPB) {
        float4 v = partials[e]; o0 += v.x; n0 += v.y; c0 += v.z; b0 += v.w;
    }
    for (int e = NBV0 + t; e < NBV0 + NBV1; e += TPB) {
        float4 v = partials[e]; o1 += v.x; n1 += v.y; c1 += v.z; b1 += v.w;
    }
    for (int e = NBV0 + NBV1 + t; e < NBLK; e += TPB) {
        float4 v = partials[e]; o2 += v.x; n2 += v.y; c2 += v.z; b2 += v.w;
    }
    o0 = wave_sum(o0); n0 = wave_sum(n0); c0 = wave_sum(c0); b0 = wave_sum(b0);
    o1 = wave_sum(o1); n1 = wave_sum(n1); c1 = wave_sum(c1); b1 = wave_sum(b1);
    o2 = wave_sum(o2); n2 = wave_sum(n2); c2 = wave_sum(c2); b2 = wave_sum(b2);
    __shared__ float s[4][12];
    int wid = t >> 6, lane = t & 63;
    if (lane == 0) {
        s[wid][0] = o0; s[wid][1] = n0; s[wid][2]  = c0; s[wid][3]  = b0;
        s[wid][4] = o1; s[wid][5] = n1; s[wid][6]  = c1; s[wid][7]  = b1;
        s[wid][8] = o2; s[wid][9] = n2; s[wid][10] = c2; s[wid][11] = b2;
    }
    __syncthreads();
    if (t == 0) {
        float r[12];
        #pragma unroll
        for (int k = 0; k < 12; ++k)
            r[k] = s[0][k] + s[1][k] + s[2][k] + s[3][k];
        float np0 = fmaxf(r[1], 1.f), np1 = fmaxf(r[5], 1.f), np2 = fmaxf(r[9], 1.f);
        float lc = r[2] / np0 + r[6] / np1 + r[10] / np2;
        float lb = r[3] / np0 + r[7] / np1 + r[11] / np2;
        float lo = r[0] / (float)C0 + r[4] / (float)C1 + r[8] / (float)C2;
        out[0] = lc + lb + lo;
        out[1] = lc;
        out[2] = lb;
        out[3] = lo;
    }
}

extern "C" void kernel_launch(void* const* d_in, const int* in_sizes, int n_in,
                              void* d_out, int out_size, void* d_ws, size_t ws_size,
                              hipStream_t stream) {
    AllPtrs p;
    p.cls0 = (const float*)d_in[0]; p.box0 = (const float*)d_in[1]; p.obj0 = (const float*)d_in[2];
    p.cls1 = (const float*)d_in[3]; p.box1 = (const float*)d_in[4]; p.obj1 = (const float*)d_in[5];
    p.cls2 = (const float*)d_in[6]; p.box2 = (const float*)d_in[7]; p.obj2 = (const float*)d_in[8];
    const float4* boxes  = (const float4*)d_in[9];
    const int*    labels = (const int*)d_in[10];
    float* out = (float*)d_out;

    // workspace: winner[CT] u32, clsmask[CT] u32 (contiguous -> one memset), partials[NBLK] float4
    char* ws = (char*)d_ws;
    unsigned* winner   = (unsigned*)ws;                   // 4,300,800 B
    unsigned* clsmask  = (unsigned*)(ws + (size_t)CT * 4);// 4,300,800 B
    float4*   partials = (float4*)(ws + (size_t)CT * 8);  // 16,800 B

    hipMemsetAsync(winner, 0, (size_t)CT * 8, stream);    // clears winner + clsmask
    scatter_boxes<<<(BATCH * 64 + TPB - 1) / TPB, TPB, 0, stream>>>(boxes, labels, winner, clsmask);
    reduce_all<<<NBLK, TPB, 0, stream>>>(p, boxes, (const uint4*)winner, clsmask, partials);
    final_combine<<<1, TPB, 0, stream>>>(partials, out);
}

// Round 7
// 35.256 us; speedup vs baseline: 5.6652x; 2.5671x over previous
//
#include <hip/hip_runtime.h>

// YOLO-style multi-level detection loss.
// Input dict order (setup_inputs interleaves!):
//   d_in[0]=cls0 d_in[1]=box0 d_in[2]=obj0
//   d_in[3]=cls1 d_in[4]=box1 d_in[5]=obj1
//   d_in[6]=cls2 d_in[7]=box2 d_in[8]=obj2
//   d_in[9]=boxes [B,N,4]  d_in[10]=labels [B,N]
// Output: 4 floats: total, loss_cls, loss_box, loss_obj
//
// bce(x,t) = bce(x,0) - x*t for t in {0,1} -> never materialize targets.
//   winner[cell]  = max over boxes of (n+1)   (atomicMax; last box wins,
//                   matching JAX CPU sequential scatter-set; 0 = negative)
//   clsmask[cell] = OR of (1<<label)          (atomicOr; exact)
// Round-3 lesson: 1 wave/SIMD = latency-bound. Round-6 lesson: libm
// log1pf/expf cost ~50 VALU instrs/cell -> VALU-bound at 78us even fully
// L3-cached. Now: __expf/__logf (v_exp/v_log, ~8 instrs) + float2/thread
// (8400 waves = 8.2/SIMD).

#define NCLS  20
#define BATCH 128
#define TPB   256
// cells per level (BATCH * H * W)
#define C0 819200
#define C1 204800
#define C2 51200
#define CT (C0 + C1 + C2)        // 1,075,200
// reduce blocks per level: cells/2/TPB (exact)
#define NBV0 1600
#define NBV1 400
#define NBV2 100
#define NBLK (NBV0 + NBV1 + NBV2)  // 2100

struct AllPtrs {
    const float *cls0, *box0, *obj0;
    const float *cls1, *box1, *obj1;
    const float *cls2, *box2, *obj2;
};

__device__ __forceinline__ float bce0(float x) {
    // bce_with_logits(x,0) = max(x,0) + log1p(exp(-|x|)); fast v_exp/v_log
    // version: for e=exp(-|x|) in (0,1], log(1+e) == log1p(e) to fp32 except
    // e < 2^-24 where abs err <= 6e-8 (vanishes in the mean over 1M cells).
    return fmaxf(x, 0.0f) + __logf(1.0f + __expf(-fabsf(x)));
}

__device__ __forceinline__ float wave_sum(float v) {
    #pragma unroll
    for (int o = 32; o > 0; o >>= 1) v += __shfl_down(v, o);
    return v;
}

__global__ void scatter_boxes(const float4* __restrict__ boxes, const int* __restrict__ labels,
                              unsigned* __restrict__ winner, unsigned* __restrict__ clsmask) {
    int t = blockIdx.x * blockDim.x + threadIdx.x;
    if (t >= BATCH * 64) return;
    int b = t >> 6;
    int n = t & 63;
    float4 bx = boxes[t];
    float cx = (bx.x + bx.z) * 0.5f;
    float cy = (bx.y + bx.w) * 0.5f;
    unsigned wv = (unsigned)(n + 1);
    unsigned lb = 1u << labels[t];
    const int   offs[3] = {0, C0, C0 + C1};
    const int   Hs[3]   = {80, 40, 20};
    const float is[3]   = {0.125f, 0.0625f, 0.03125f};
    #pragma unroll
    for (int l = 0; l < 3; ++l) {
        int H = Hs[l], W = Hs[l];
        int gx = (int)floorf(cx * is[l]);
        int gy = (int)floorf(cy * is[l]);
        if (gx >= 0 && gy >= 0 && gx < W && gy < H) {
            int cell = offs[l] + (b * H + gy) * W + gx;
            atomicMax(winner + cell, wv);
            atomicOr(clsmask + cell, lb);
        }
    }
}

struct Acc { float obj, np, cls, box; };

template<int HW>
__device__ __forceinline__ void proc2(int i, float2 ov, uint2 wq,
                                      const unsigned* __restrict__ clsmask,
                                      const float* __restrict__ cls,
                                      const float* __restrict__ boxp,
                                      const float4* __restrict__ boxes,
                                      float inv_stride, Acc& a) {
    const float    o[2] = {ov.x, ov.y};
    const unsigned g[2] = {wq.x, wq.y};
    #pragma unroll
    for (int j = 0; j < 2; ++j) {
        float x = o[j];
        float v = bce0(x);                 // bce(obj, 0)
        if (g[j]) {                        // positive cell (~1%)
            int cell = i * 2 + j;
            int b = cell / HW, rem = cell - b * HW;   // HW compile-time -> magic mul
            int wn = (int)g[j] - 1;
            unsigned m = clsmask[cell];
            v -= x;                        // -> bce(obj, 1)
            a.np += 1.f;
            const float* cb = cls + (b * NCLS) * HW + rem;
            #pragma unroll
            for (int c = 0; c < NCLS; ++c) {
                float cv = cb[c * HW];
                a.cls += bce0(cv);
                if ((m >> c) & 1u) a.cls -= cv;   // bce(cv,1) = bce(cv,0) - cv
            }
            float4 bx = boxes[(b << 6) + wn];
            float cx = (bx.x + bx.z) * 0.5f, cy = (bx.y + bx.w) * 0.5f;
            float w  = bx.z - bx.x,          h  = bx.w - bx.y;
            float sx = cx * inv_stride,      sy = cy * inv_stride;
            float tv0 = sx - floorf(sx);
            float tv1 = sy - floorf(sy);
            float tv2 = __logf(w * inv_stride + 1e-6f);
            float tv3 = __logf(h * inv_stride + 1e-6f);
            const float* pb = boxp + (b * 4) * HW + rem;
            float d0 = fabsf(pb[0]      - tv0);
            float d1 = fabsf(pb[HW]     - tv1);
            float d2 = fabsf(pb[2 * HW] - tv2);
            float d3 = fabsf(pb[3 * HW] - tv3);
            a.box += (d0 < 1.f) ? 0.5f * d0 * d0 : d0 - 0.5f;
            a.box += (d1 < 1.f) ? 0.5f * d1 * d1 : d1 - 0.5f;
            a.box += (d2 < 1.f) ? 0.5f * d2 * d2 : d2 - 0.5f;
            a.box += (d3 < 1.f) ? 0.5f * d3 * d3 : d3 - 0.5f;
        }
        a.obj += v;
    }
}

__global__ void __launch_bounds__(TPB)
reduce_all(AllPtrs p, const float4* __restrict__ boxes,
           const uint2* __restrict__ winner2, const unsigned* __restrict__ clsmask,
           float4* __restrict__ partials) {
    int blk = blockIdx.x;
    Acc a = {0.f, 0.f, 0.f, 0.f};
    if (blk < NBV0) {
        int i = blk * TPB + threadIdx.x;
        proc2<6400>(i, ((const float2*)p.obj0)[i], winner2[i], clsmask,
                    p.cls0, p.box0, boxes, 0.125f, a);
    } else if (blk < NBV0 + NBV1) {
        int i = (blk - NBV0) * TPB + threadIdx.x;
        proc2<1600>(i, ((const float2*)p.obj1)[i], winner2[C0 / 2 + i], clsmask + C0,
                    p.cls1, p.box1, boxes, 0.0625f, a);
    } else {
        int i = (blk - NBV0 - NBV1) * TPB + threadIdx.x;
        proc2<400>(i, ((const float2*)p.obj2)[i], winner2[(C0 + C1) / 2 + i], clsmask + C0 + C1,
                    p.cls2, p.box2, boxes, 0.03125f, a);
    }
    float ro = wave_sum(a.obj), rn = wave_sum(a.np);
    float rc = wave_sum(a.cls), rb = wave_sum(a.box);
    __shared__ float s[TPB / 64][4];
    int wid = threadIdx.x >> 6, lane = threadIdx.x & 63;
    if (lane == 0) { s[wid][0] = ro; s[wid][1] = rn; s[wid][2] = rc; s[wid][3] = rb; }
    __syncthreads();
    if (threadIdx.x == 0) {
        float o = 0, np = 0, c = 0, bo = 0;
        #pragma unroll
        for (int w = 0; w < TPB / 64; ++w) {
            o += s[w][0]; np += s[w][1]; c += s[w][2]; bo += s[w][3];
        }
        partials[blk] = make_float4(o, np, c, bo);
    }
}

__global__ void final_combine(const float4* __restrict__ partials, float* __restrict__ out) {
    int t = threadIdx.x;
    float o0 = 0, n0 = 0, c0 = 0, b0 = 0;
    float o1 = 0, n1 = 0, c1 = 0, b1 = 0;
    float o2 = 0, n2 = 0, c2 = 0, b2 = 0;
    for (int e = t; e < NBV0; e += TPB) {
        float4 v = partials[e]; o0 += v.x; n0 += v.y; c0 += v.z; b0 += v.w;
    }
    for (int e = NBV0 + t; e < NBV0 + NBV1; e += TPB) {
        float4 v = partials[e]; o1 += v.x; n1 += v.y; c1 += v.z; b1 += v.w;
    }
    for (int e = NBV0 + NBV1 + t; e < NBLK; e += TPB) {
        float4 v = partials[e]; o2 += v.x; n2 += v.y; c2 += v.z; b2 += v.w;
    }
    o0 = wave_sum(o0); n0 = wave_sum(n0); c0 = wave_sum(c0); b0 = wave_sum(b0);
    o1 = wave_sum(o1); n1 = wave_sum(n1); c1 = wave_sum(c1); b1 = wave_sum(b1);
    o2 = wave_sum(o2); n2 = wave_sum(n2); c2 = wave_sum(c2); b2 = wave_sum(b2);
    __shared__ float s[4][12];
    int wid = t >> 6, lane = t & 63;
    if (lane == 0) {
        s[wid][0] = o0; s[wid][1] = n0; s[wid][2]  = c0; s[wid][3]  = b0;
        s[wid][4] = o1; s[wid][5] = n1; s[wid][6]  = c1; s[wid][7]  = b1;
        s[wid][8] = o2; s[wid][9] = n2; s[wid][10] = c2; s[wid][11] = b2;
    }
    __syncthreads();
    if (t == 0) {
        float r[12];
        #pragma unroll
        for (int k = 0; k < 12; ++k)
            r[k] = s[0][k] + s[1][k] + s[2][k] + s[3][k];
        float np0 = fmaxf(r[1], 1.f), np1 = fmaxf(r[5], 1.f), np2 = fmaxf(r[9], 1.f);
        float lc = r[2] / np0 + r[6] / np1 + r[10] / np2;
        float lb = r[3] / np0 + r[7] / np1 + r[11] / np2;
        float lo = r[0] / (float)C0 + r[4] / (float)C1 + r[8] / (float)C2;
        out[0] = lc + lb + lo;
        out[1] = lc;
        out[2] = lb;
        out[3] = lo;
    }
}

extern "C" void kernel_launch(void* const* d_in, const int* in_sizes, int n_in,
                              void* d_out, int out_size, void* d_ws, size_t ws_size,
                              hipStream_t stream) {
    AllPtrs p;
    p.cls0 = (const float*)d_in[0]; p.box0 = (const float*)d_in[1]; p.obj0 = (const float*)d_in[2];
    p.cls1 = (const float*)d_in[3]; p.box1 = (const float*)d_in[4]; p.obj1 = (const float*)d_in[5];
    p.cls2 = (const float*)d_in[6]; p.box2 = (const float*)d_in[7]; p.obj2 = (const float*)d_in[8];
    const float4* boxes  = (const float4*)d_in[9];
    const int*    labels = (const int*)d_in[10];
    float* out = (float*)d_out;

    // workspace: winner[CT] u32, clsmask[CT] u32 (contiguous -> one memset), partials[NBLK] float4
    char* ws = (char*)d_ws;
    unsigned* winner   = (unsigned*)ws;                   // 4,300,800 B
    unsigned* clsmask  = (unsigned*)(ws + (size_t)CT * 4);// 4,300,800 B
    float4*   partials = (float4*)(ws + (size_t)CT * 8);  // 33,600 B

    hipMemsetAsync(winner, 0, (size_t)CT * 8, stream);    // clears winner + clsmask
    scatter_boxes<<<(BATCH * 64 + TPB - 1) / TPB, TPB, 0, stream>>>(boxes, labels, winner, clsmask);
    reduce_all<<<NBLK, TPB, 0, stream>>>(p, boxes, (const uint2*)winner, clsmask, partials);
    final_combine<<<1, TPB, 0, stream>>>(partials, out);
}